// Round 1
// baseline (1077.989 us; speedup 1.0000x reference)
//
#include <hip/hip_runtime.h>
#include <cstddef>
#include <cstdint>

#define BB 4
#define HH 8
#define HEADD 64
#define DIMM 512
#define XLL 1024
#define KLL 256
#define BHH (BB*HH)
#define SCALEF 0.125f

// ---------------------------------------------------------------------------
// GEMM: C = A[M,512] @ W[512,1536], epilogue splits into q/k/v per-head
// layout [b, h, n, 64].  Tile 64x64, 256 threads, 4x4 micro-tile, BK=16.
// ---------------------------------------------------------------------------
__global__ __launch_bounds__(256) void gemm_qkv_k(
    const float* __restrict__ A, const float* __restrict__ W,
    float* __restrict__ qb, float* __restrict__ kb, float* __restrict__ vb,
    int M, int seq)
{
    const int N = 3 * DIMM, K = DIMM;
    __shared__ float As[64][17];
    __shared__ float Bs[16][64];
    const int tid = threadIdx.x;
    const int tr = tid >> 4, tc = tid & 15;
    const int rb = blockIdx.y * 64;
    const int cb = blockIdx.x * 64;
    float acc[4][4] = {};
    for (int k0 = 0; k0 < K; k0 += 16) {
        {
            int e = tid * 4;
            int r = e >> 4, kk = e & 15;
            float4 av = *reinterpret_cast<const float4*>(A + (size_t)(rb + r) * K + k0 + kk);
            As[r][kk + 0] = av.x; As[r][kk + 1] = av.y; As[r][kk + 2] = av.z; As[r][kk + 3] = av.w;
            int kk2 = e >> 6, c = e & 63;
            float4 bv = *reinterpret_cast<const float4*>(W + (size_t)(k0 + kk2) * N + cb + c);
            *reinterpret_cast<float4*>(&Bs[kk2][c]) = bv;
        }
        __syncthreads();
        #pragma unroll
        for (int kk = 0; kk < 16; ++kk) {
            float a[4], bw[4];
            #pragma unroll
            for (int i = 0; i < 4; ++i) a[i] = As[tr * 4 + i][kk];
            #pragma unroll
            for (int j = 0; j < 4; ++j) bw[j] = Bs[kk][tc * 4 + j];
            #pragma unroll
            for (int i = 0; i < 4; ++i)
                #pragma unroll
                for (int j = 0; j < 4; ++j)
                    acc[i][j] = fmaf(a[i], bw[j], acc[i][j]);
        }
        __syncthreads();
    }
    #pragma unroll
    for (int i = 0; i < 4; ++i) {
        int m = rb + tr * 4 + i;
        int bi = m / seq, n = m % seq;
        #pragma unroll
        for (int j = 0; j < 4; ++j) {
            int c = cb + tc * 4 + j;
            int which = c >> 9;          // 0=q 1=k 2=v
            int h = (c & 511) >> 6;
            int d = c & 63;
            float* dst = which == 0 ? qb : (which == 1 ? kb : vb);
            if (dst)
                dst[(((size_t)bi * HH + h) * seq + n) * HEADD + d] = acc[i][j];
        }
    }
}

// ---------------------------------------------------------------------------
// GEMM: out[M,512] = A[M,512] @ W[512,512] + bscale * bias
// ---------------------------------------------------------------------------
__global__ __launch_bounds__(256) void gemm_proj_k(
    const float* __restrict__ A, const float* __restrict__ W,
    const float* __restrict__ bias, float bscale,
    float* __restrict__ out, int M)
{
    const int N = DIMM, K = DIMM;
    __shared__ float As[64][17];
    __shared__ float Bs[16][64];
    const int tid = threadIdx.x;
    const int tr = tid >> 4, tc = tid & 15;
    const int rb = blockIdx.y * 64;
    const int cb = blockIdx.x * 64;
    float acc[4][4] = {};
    for (int k0 = 0; k0 < K; k0 += 16) {
        {
            int e = tid * 4;
            int r = e >> 4, kk = e & 15;
            float4 av = *reinterpret_cast<const float4*>(A + (size_t)(rb + r) * K + k0 + kk);
            As[r][kk + 0] = av.x; As[r][kk + 1] = av.y; As[r][kk + 2] = av.z; As[r][kk + 3] = av.w;
            int kk2 = e >> 6, c = e & 63;
            float4 bv = *reinterpret_cast<const float4*>(W + (size_t)(k0 + kk2) * N + cb + c);
            *reinterpret_cast<float4*>(&Bs[kk2][c]) = bv;
        }
        __syncthreads();
        #pragma unroll
        for (int kk = 0; kk < 16; ++kk) {
            float a[4], bw[4];
            #pragma unroll
            for (int i = 0; i < 4; ++i) a[i] = As[tr * 4 + i][kk];
            #pragma unroll
            for (int j = 0; j < 4; ++j) bw[j] = Bs[kk][tc * 4 + j];
            #pragma unroll
            for (int i = 0; i < 4; ++i)
                #pragma unroll
                for (int j = 0; j < 4; ++j)
                    acc[i][j] = fmaf(a[i], bw[j], acc[i][j]);
        }
        __syncthreads();
    }
    #pragma unroll
    for (int i = 0; i < 4; ++i) {
        int m = rb + tr * 4 + i;
        #pragma unroll
        for (int j = 0; j < 4; ++j) {
            int c = cb + tc * 4 + j;
            out[(size_t)m * N + c] = acc[i][j] + bscale * bias[c];
        }
    }
}

// ---------------------------------------------------------------------------
// Batched scores: S[bh, r, c] = SCALE * sum_d Aq[bh, r, d] * Bk[bh, c, d]
// ---------------------------------------------------------------------------
__global__ __launch_bounds__(256) void scores_k(
    const float* __restrict__ Aq, const float* __restrict__ Bk,
    float* __restrict__ S, int R, int C)
{
    __shared__ float As[64][65];
    __shared__ float Bs[64][65];
    const int bh = blockIdx.z;
    const int tid = threadIdx.x;
    const int tr = tid >> 4, tc = tid & 15;
    const int rb = blockIdx.y * 64, cb = blockIdx.x * 64;
    const float* Ap = Aq + (size_t)bh * R * HEADD;
    const float* Bp = Bk + (size_t)bh * C * HEADD;
    #pragma unroll
    for (int u = 0; u < 4; ++u) {
        int e = (tid + u * 256) * 4;
        int r = e >> 6, d = e & 63;
        float4 a4 = *reinterpret_cast<const float4*>(Ap + (size_t)(rb + r) * HEADD + d);
        As[r][d + 0] = a4.x; As[r][d + 1] = a4.y; As[r][d + 2] = a4.z; As[r][d + 3] = a4.w;
        float4 b4 = *reinterpret_cast<const float4*>(Bp + (size_t)(cb + r) * HEADD + d);
        Bs[r][d + 0] = b4.x; Bs[r][d + 1] = b4.y; Bs[r][d + 2] = b4.z; Bs[r][d + 3] = b4.w;
    }
    __syncthreads();
    float acc[4][4] = {};
    #pragma unroll 16
    for (int kk = 0; kk < 64; ++kk) {
        float a[4], b[4];
        #pragma unroll
        for (int i = 0; i < 4; ++i) a[i] = As[tr * 4 + i][kk];
        #pragma unroll
        for (int j = 0; j < 4; ++j) b[j] = Bs[tc * 4 + j][kk];
        #pragma unroll
        for (int i = 0; i < 4; ++i)
            #pragma unroll
            for (int j = 0; j < 4; ++j)
                acc[i][j] = fmaf(a[i], b[j], acc[i][j]);
    }
    #pragma unroll
    for (int i = 0; i < 4; ++i) {
        int r = rb + tr * 4 + i;
        #pragma unroll
        for (int j = 0; j < 4; ++j) {
            int c = cb + tc * 4 + j;
            S[((size_t)bh * R + r) * C + c] = acc[i][j] * SCALEF;
        }
    }
}

// ---------------------------------------------------------------------------
// Batched PV: out_merged[(b*R + r)*512 + h*64 + d] (+)= sum_c P[bh,r,c]*V[bh,c,d]
// ---------------------------------------------------------------------------
template<bool ACCUM>
__global__ __launch_bounds__(256) void pv_k(
    const float* __restrict__ P, const float* __restrict__ V,
    float* __restrict__ out, int R, int C)
{
    __shared__ float Ps[64][65];
    __shared__ float Vs[64][65];
    const int bh = blockIdx.y, b = bh >> 3, h = bh & 7;
    const int tid = threadIdx.x;
    const int tr = tid >> 4, tc = tid & 15;
    const int rb = blockIdx.x * 64;
    float acc[4][4] = {};
    for (int c0 = 0; c0 < C; c0 += 64) {
        #pragma unroll
        for (int u = 0; u < 4; ++u) {
            int e = (tid + u * 256) * 4;
            int r = e >> 6, d = e & 63;
            float4 p4 = *reinterpret_cast<const float4*>(P + ((size_t)bh * R + rb + r) * C + c0 + d);
            Ps[r][d + 0] = p4.x; Ps[r][d + 1] = p4.y; Ps[r][d + 2] = p4.z; Ps[r][d + 3] = p4.w;
            float4 v4 = *reinterpret_cast<const float4*>(V + ((size_t)bh * C + c0 + r) * HEADD + d);
            Vs[r][d + 0] = v4.x; Vs[r][d + 1] = v4.y; Vs[r][d + 2] = v4.z; Vs[r][d + 3] = v4.w;
        }
        __syncthreads();
        #pragma unroll 16
        for (int kk = 0; kk < 64; ++kk) {
            float a[4], v[4];
            #pragma unroll
            for (int i = 0; i < 4; ++i) a[i] = Ps[tr * 4 + i][kk];
            #pragma unroll
            for (int j = 0; j < 4; ++j) v[j] = Vs[kk][tc * 4 + j];
            #pragma unroll
            for (int i = 0; i < 4; ++i)
                #pragma unroll
                for (int j = 0; j < 4; ++j)
                    acc[i][j] = fmaf(a[i], v[j], acc[i][j]);
        }
        __syncthreads();
    }
    #pragma unroll
    for (int i = 0; i < 4; ++i) {
        int r = rb + tr * 4 + i;
        #pragma unroll
        for (int j = 0; j < 4; ++j) {
            int d = tc * 4 + j;
            size_t o = ((size_t)(b * R + r)) * DIMM + h * HEADD + d;
            if (ACCUM) out[o] += acc[i][j];
            else       out[o]  = acc[i][j];
        }
    }
}

// ---------------------------------------------------------------------------
// main orientation: per (bh, k) sum |S[bh,k,x]| into 8 polar bins, argmax.
// ---------------------------------------------------------------------------
__global__ __launch_bounds__(256) void main_ori_k(
    const float* __restrict__ S, const int* __restrict__ polar,
    int* __restrict__ MO)
{
    const int blk = blockIdx.x;          // bh*KLL + k
    const int bh = blk >> 8;
    const int k = blk & 255;
    const int b = bh >> 3;
    const int tid = threadIdx.x;
    const float* row = S + (size_t)blk * XLL;
    const int* prow = polar + ((size_t)b * KLL + k) * XLL;
    float bins[8] = {};
    for (int x = tid; x < XLL; x += 256) {
        float v = fabsf(row[x]);
        int p = prow[x]; p = p < 0 ? 0 : (p > 7 ? 7 : p);
        #pragma unroll
        for (int o = 0; o < 8; ++o) bins[o] += (p == o) ? v : 0.0f;
    }
    __shared__ float red[256][8];
    #pragma unroll
    for (int o = 0; o < 8; ++o) red[tid][o] = bins[o];
    __syncthreads();
    for (int off = 128; off > 0; off >>= 1) {
        if (tid < off) {
            #pragma unroll
            for (int o = 0; o < 8; ++o) red[tid][o] += red[tid + off][o];
        }
        __syncthreads();
    }
    if (tid == 0) {
        int best = 0; float bv = red[0][0];
        #pragma unroll
        for (int o = 1; o < 8; ++o) if (red[0][o] > bv) { bv = red[0][o]; best = o; }
        MO[blk] = best;
    }
}

// ---------------------------------------------------------------------------
// In-place masked/biased softmax over rows of S[bh, R, CC].
// BIASMODE: 0 none; 1 row-index is k (S is [kl, xl]); 2 col-index is k.
// MASKT: mask laid out [b,h,C,R] (access [c, r]) instead of [b,h,R,C].
// ---------------------------------------------------------------------------
template<int BIASMODE, int MASKT, int CC>
__global__ __launch_bounds__(256) void softmax_k(
    float* __restrict__ S, const int* __restrict__ mask, float maskval,
    const int* __restrict__ rd, const int* __restrict__ polar,
    const float* __restrict__ dis, const float* __restrict__ pemb,
    const int* __restrict__ MO, int R)
{
    constexpr int NP = CC / 256;
    const int blk = blockIdx.x;          // bh*R + r
    const int bh = blk / R;
    const int r = blk - bh * R;
    const int b = bh >> 3, h = bh & 7;
    const int tid = threadIdx.x;
    float* row = S + (size_t)blk * CC;
    float vals[NP];
    float lmax = -3.4e38f;
    #pragma unroll
    for (int u = 0; u < NP; ++u) {
        int c = tid + u * 256;
        float s = row[c];
        size_t midx = MASKT ? ((size_t)bh * CC + c) * R + r : (size_t)blk * CC + c;
        if (mask[midx]) s = maskval;
        if (BIASMODE) {
            int kk = (BIASMODE == 1) ? r : c;
            int xx = (BIASMODE == 1) ? c : r;
            size_t pidx = ((size_t)b * KLL + kk) * XLL + xx;
            int rv = rd[pidx];
            int pv = polar[pidx]; pv = pv < 0 ? 0 : (pv > 7 ? 7 : pv);
            int mo = MO[bh * KLL + kk];
            int np = pv - mo; if (np < 0) np += 8;
            s += dis[rv * HH + h] + pemb[np];
        }
        vals[u] = s;
        lmax = fmaxf(lmax, s);
    }
    __shared__ float red[256];
    red[tid] = lmax; __syncthreads();
    for (int off = 128; off > 0; off >>= 1) {
        if (tid < off) red[tid] = fmaxf(red[tid], red[tid + off]);
        __syncthreads();
    }
    float m = red[0]; __syncthreads();
    float lsum = 0.0f;
    #pragma unroll
    for (int u = 0; u < NP; ++u) { vals[u] = __expf(vals[u] - m); lsum += vals[u]; }
    red[tid] = lsum; __syncthreads();
    for (int off = 128; off > 0; off >>= 1) {
        if (tid < off) red[tid] += red[tid + off];
        __syncthreads();
    }
    float inv = 1.0f / red[0];
    #pragma unroll
    for (int u = 0; u < NP; ++u) row[tid + u * 256] = vals[u] * inv;
}

// ---------------------------------------------------------------------------
extern "C" void kernel_launch(void* const* d_in, const int* in_sizes, int n_in,
                              void* d_out, int out_size, void* d_ws, size_t ws_size,
                              hipStream_t stream)
{
    const float* x        = (const float*)d_in[0];
    const float* kernal   = (const float*)d_in[1];
    const float* i_x      = (const float*)d_in[2];
    const float* i_kernal = (const float*)d_in[3];
    const int*   rd       = (const int*)d_in[4];
    const int*   polar    = (const int*)d_in[5];
    const int*   att      = (const int*)d_in[6];
    const int*   i_att    = (const int*)d_in[7];
    const int*   cross    = (const int*)d_in[8];
    const float* Wqkv     = (const float*)d_in[9];
    const float* Wqkv_i   = (const float*)d_in[10];
    const float* Wqkv_i2  = (const float*)d_in[11];
    const float* Wproj    = (const float*)d_in[12];
    const float* bproj    = (const float*)d_in[13];
    const float* Wproj_i  = (const float*)d_in[14];
    const float* bproj_i  = (const float*)d_in[15];
    const float* Wproj_i2 = (const float*)d_in[16];
    const float* bproj_i2 = (const float*)d_in[17];
    const float* dis      = (const float*)d_in[18];
    const float* pemb     = (const float*)d_in[19];

    float* out = (float*)d_out;
    float* x_out   = out;                         // [4,1024,512]
    float* k_out   = out + (size_t)BB * XLL * DIMM;           // [4,256,512]
    float* i_x_out = k_out + (size_t)BB * KLL * DIMM;         // [4,1024,512]

    const size_t NQX = (size_t)BB * HH * XLL * HEADD;  // 2,097,152
    const size_t NQK = (size_t)BB * HH * KLL * HEADD;  //   524,288
    const size_t NS  = (size_t)BHH * KLL * XLL;        // 8,388,608
    const size_t NMK = (size_t)BB * KLL * DIMM;        //   524,288
    const size_t NMX = (size_t)BB * XLL * DIMM;        // 2,097,152

    float* ws = (float*)d_ws;
    size_t off = 0;
    auto alloc = [&](size_t n) { float* p = ws + off; off += n; return p; };
    float* Q    = alloc(NQX);
    float* KXb  = alloc(NQX);
    float* VXb  = alloc(NQX);
    float* KQb  = alloc(NQK);
    float* KKb  = alloc(NQK);
    float* KVb  = alloc(NQK);
    float* IQ   = alloc(NQX);
    float* IKb  = alloc(NQX);
    float* IVb  = alloc(NQX);
    float* IKQ  = alloc(NQK);
    float* IKK  = alloc(NQK);
    float* IKV  = alloc(NQK);
    float* S    = alloc(NS);
    float* KM   = alloc(NMK);   // merged kernal-side attention (reused)
    float* XM   = alloc(NMX);   // merged x-side attention (reused)
    float* IKOUT= alloc(NMK);
    int*   MO   = (int*)alloc(BHH * KLL);

    dim3 blk(256);

    // 1-4: QKV projections
    gemm_qkv_k<<<dim3(24, 64), blk, 0, stream>>>(x,        Wqkv,   Q,   KXb, VXb, BB*XLL, XLL);
    gemm_qkv_k<<<dim3(24, 16), blk, 0, stream>>>(kernal,   Wqkv,   KQb, KKb, KVb, BB*KLL, KLL);
    gemm_qkv_k<<<dim3(24, 64), blk, 0, stream>>>(i_x,      Wqkv_i, IQ,  IKb, IVb, BB*XLL, XLL);
    gemm_qkv_k<<<dim3(24, 16), blk, 0, stream>>>(i_kernal, Wqkv_i, IKQ, IKK, IKV, BB*KLL, KLL);

    // --- branch 1: k_out ---
    // 5: S = k_q @ k^T * SCALE   [bh, 256, 1024]
    scores_k<<<dim3(XLL/64, KLL/64, BHH), blk, 0, stream>>>(KQb, KXb, S, KLL, XLL);
    // 6: main orientation
    main_ori_k<<<dim3(BHH * KLL), blk, 0, stream>>>(S, polar, MO);
    // 7: softmax over x with maskT(-1e6) + rd/polar bias (row = k)
    softmax_k<1, 1, XLL><<<dim3(BHH * KLL), blk, 0, stream>>>(S, att, -1e6f, rd, polar, dis, pemb, MO, KLL);
    // 8: katt = S @ v  -> merged KM
    pv_k<false><<<dim3(KLL/64, BHH), blk, 0, stream>>>(S, VXb, KM, KLL, XLL);
    // 9: k_out = KM @ Wproj + bproj
    gemm_proj_k<<<dim3(8, 16), blk, 0, stream>>>(KM, Wproj, bproj, 1.0f, k_out, BB*KLL);

    // --- branch 2: x_out ---
    // 10: S = q @ k_k^T * SCALE [bh, 1024, 256]
    scores_k<<<dim3(KLL/64, XLL/64, BHH), blk, 0, stream>>>(Q, KKb, S, XLL, KLL);
    // 11: softmax over k, mask direct (-1e9), bias with col = k
    softmax_k<2, 0, KLL><<<dim3(BHH * XLL), blk, 0, stream>>>(S, att, -1e9f, rd, polar, dis, pemb, MO, XLL);
    // 12: att1 = S @ k_v -> XM
    pv_k<false><<<dim3(XLL/64, BHH), blk, 0, stream>>>(S, KVb, XM, XLL, KLL);
    // 13: S = q @ i_k_k^T * SCALE
    scores_k<<<dim3(KLL/64, XLL/64, BHH), blk, 0, stream>>>(Q, IKK, S, XLL, KLL);
    // 14: softmax over k, cross mask (-1e9), no bias
    softmax_k<0, 0, KLL><<<dim3(BHH * XLL), blk, 0, stream>>>(S, cross, -1e9f, rd, polar, dis, pemb, MO, XLL);
    // 15: att2 accumulate into XM
    pv_k<true><<<dim3(XLL/64, BHH), blk, 0, stream>>>(S, IKV, XM, XLL, KLL);
    // 16: x_out = XM @ Wproj + 2*bproj
    gemm_proj_k<<<dim3(8, 64), blk, 0, stream>>>(XM, Wproj, bproj, 2.0f, x_out, BB*XLL);

    // --- branch 3: i_x_out ---
    // 17: S = i_k_q @ i_k^T * SCALE [bh, 256, 1024]
    scores_k<<<dim3(XLL/64, KLL/64, BHH), blk, 0, stream>>>(IKQ, IKb, S, KLL, XLL);
    // 18: softmax over x, i_att maskT (-1e9), no bias
    softmax_k<0, 1, XLL><<<dim3(BHH * KLL), blk, 0, stream>>>(S, i_att, -1e9f, rd, polar, dis, pemb, MO, KLL);
    // 19: ikatt = S @ i_v -> KM (reuse)
    pv_k<false><<<dim3(KLL/64, BHH), blk, 0, stream>>>(S, IVb, KM, KLL, XLL);
    // 20: i_k_out = KM @ Wproj_i + bproj_i -> IKOUT
    gemm_proj_k<<<dim3(8, 16), blk, 0, stream>>>(KM, Wproj_i, bproj_i, 1.0f, IKOUT, BB*KLL);
    // 21: qkv(i_k_out, Wqkv_i2): k -> KQb slot, v -> KKb slot (both dead)
    gemm_qkv_k<<<dim3(24, 16), blk, 0, stream>>>(IKOUT, Wqkv_i2, nullptr, KQb, KKb, BB*KLL, KLL);
    // 22: S = i_q @ i_k2_k^T * SCALE [bh, 1024, 256]
    scores_k<<<dim3(KLL/64, XLL/64, BHH), blk, 0, stream>>>(IQ, KQb, S, XLL, KLL);
    // 23: softmax over k, i_att direct (-1e9)
    softmax_k<0, 0, KLL><<<dim3(BHH * XLL), blk, 0, stream>>>(S, i_att, -1e9f, rd, polar, dis, pemb, MO, XLL);
    // 24: iatt = S @ i_k2_v -> XM (reuse)
    pv_k<false><<<dim3(XLL/64, BHH), blk, 0, stream>>>(S, KKb, XM, XLL, KLL);
    // 25: i_x_out = XM @ Wproj_i2 + bproj_i2
    gemm_proj_k<<<dim3(8, 64), blk, 0, stream>>>(XM, Wproj_i2, bproj_i2, 1.0f, i_x_out, BB*XLL);

    (void)in_sizes; (void)n_in; (void)out_size; (void)ws_size;
}

// Round 2
// 488.736 us; speedup vs baseline: 2.2057x; 2.2057x over previous
//
#include <hip/hip_runtime.h>
#include <cstddef>
#include <cstdint>

#define BB 4
#define HH 8
#define HEADD 64
#define DIMM 512
#define XLL 1024
#define KLL 256
#define BHH (BB*HH)
#define SCALEF 0.125f

typedef __attribute__((ext_vector_type(8))) short bf16x8;
typedef __attribute__((ext_vector_type(8))) unsigned short u16x8;
typedef __attribute__((ext_vector_type(4))) float f32x4;
typedef unsigned short u16;

__device__ __forceinline__ u16 f2b(float f) {
    unsigned int u = __builtin_bit_cast(unsigned int, f);
    u = u + 0x7fffu + ((u >> 16) & 1u);
    return (u16)(u >> 16);
}
__device__ __forceinline__ float b2f(u16 h) {
    unsigned int u = ((unsigned int)h) << 16;
    return __builtin_bit_cast(float, u);
}
__device__ __forceinline__ f32x4 mfma16(bf16x8 a, bf16x8 b, f32x4 c) {
    // gfx950 16x16x32 bf16. Assumed operand layout: lane l supplies
    // A[row=l&15][k=8*(l>>4)+j] (contiguous 8 in K), B[k=8*(l>>4)+j][col=l&15];
    // D: row=(l>>4)*4+reg, col=l&15 (verified layout per guide m89).
    return __builtin_amdgcn_mfma_f32_16x16x32_bf16(a, b, c, 0, 0, 0);
}
__device__ __forceinline__ float wred_max(float v) {
    #pragma unroll
    for (int o = 1; o < 64; o <<= 1) v = fmaxf(v, __shfl_xor(v, o, 64));
    return v;
}
__device__ __forceinline__ float wred_sum(float v) {
    #pragma unroll
    for (int o = 1; o < 64; o <<= 1) v += __shfl_xor(v, o, 64);
    return v;
}

// ---------------------------------------------------------------------------
// f32 -> bf16 cast, 8 elems/thread
// ---------------------------------------------------------------------------
__global__ __launch_bounds__(256) void cast_bf16_k(
    const float* __restrict__ in, u16* __restrict__ out, int n8)
{
    int i = blockIdx.x * 256 + threadIdx.x;
    if (i >= n8) return;
    const float4* p = reinterpret_cast<const float4*>(in) + (size_t)i * 2;
    float4 a = p[0], b = p[1];
    u16x8 o;
    o[0] = f2b(a.x); o[1] = f2b(a.y); o[2] = f2b(a.z); o[3] = f2b(a.w);
    o[4] = f2b(b.x); o[5] = f2b(b.y); o[6] = f2b(b.z); o[7] = f2b(b.w);
    *reinterpret_cast<u16x8*>(out + (size_t)i * 8) = o;
}

// ---------------------------------------------------------------------------
// W [K][N] f32  ->  Wt [N][K] bf16
// ---------------------------------------------------------------------------
__global__ __launch_bounds__(256) void transpose_cast_k(
    const float* __restrict__ W, u16* __restrict__ Wt, int K, int N)
{
    __shared__ float t[32][33];
    int bx = blockIdx.x, by = blockIdx.y;
    int tx = threadIdx.x & 31, ty = threadIdx.x >> 5;
    #pragma unroll
    for (int r = ty; r < 32; r += 8)
        t[r][tx] = W[(size_t)(by * 32 + r) * N + bx * 32 + tx];
    __syncthreads();
    #pragma unroll
    for (int r = ty; r < 32; r += 8)
        Wt[(size_t)(bx * 32 + r) * K + by * 32 + tx] = f2b(t[tx][r]);
}

// ---------------------------------------------------------------------------
// QKV GEMM: A bf16 [M,512] @ Wt bf16 [1536,512]^T, epilogue split per head.
// q,k -> [b,h,n,64] bf16; v -> [b,h,64,n] bf16 (transposed for PV B-operand)
// ---------------------------------------------------------------------------
__global__ __launch_bounds__(256) void gemm_qkv_mfma_k(
    const u16* __restrict__ A, const u16* __restrict__ Wt,
    u16* __restrict__ qb, u16* __restrict__ kb, u16* __restrict__ vt,
    int sl)
{
    __shared__ __align__(16) short As[128][72];
    __shared__ __align__(16) short Bs[128][72];
    const int tid = threadIdx.x;
    const int wave = tid >> 6, lane = tid & 63;
    const int lr = lane & 15, lk = (lane >> 4) * 8;
    const int rb = blockIdx.y * 128, cb = blockIdx.x * 128;
    const int wr = (wave >> 1) * 64, wc = (wave & 1) * 64;
    const int seq = 1 << sl, smask = seq - 1;
    f32x4 acc[4][4] = {};
    const int srow = tid >> 3, skc = (tid & 7) * 8;
    for (int k0 = 0; k0 < 512; k0 += 64) {
        #pragma unroll
        for (int it = 0; it < 4; ++it) {
            int row = it * 32 + srow;
            *reinterpret_cast<bf16x8*>(&As[row][skc]) =
                *reinterpret_cast<const bf16x8*>(A + (size_t)(rb + row) * 512 + k0 + skc);
            *reinterpret_cast<bf16x8*>(&Bs[row][skc]) =
                *reinterpret_cast<const bf16x8*>(Wt + (size_t)(cb + row) * 512 + k0 + skc);
        }
        __syncthreads();
        #pragma unroll
        for (int ks = 0; ks < 2; ++ks) {
            bf16x8 af[4], bf_[4];
            #pragma unroll
            for (int mi = 0; mi < 4; ++mi)
                af[mi] = *reinterpret_cast<const bf16x8*>(&As[wr + mi * 16 + lr][ks * 32 + lk]);
            #pragma unroll
            for (int ni = 0; ni < 4; ++ni)
                bf_[ni] = *reinterpret_cast<const bf16x8*>(&Bs[wc + ni * 16 + lr][ks * 32 + lk]);
            #pragma unroll
            for (int mi = 0; mi < 4; ++mi)
                #pragma unroll
                for (int ni = 0; ni < 4; ++ni)
                    acc[mi][ni] = mfma16(af[mi], bf_[ni], acc[mi][ni]);
        }
        __syncthreads();
    }
    #pragma unroll
    for (int mi = 0; mi < 4; ++mi) {
        int m0 = rb + wr + mi * 16 + (lane >> 4) * 4;
        #pragma unroll
        for (int ni = 0; ni < 4; ++ni) {
            int c = cb + wc + ni * 16 + lr;
            int which = c >> 9, h = (c >> 6) & 7, d = c & 63;
            f32x4 v = acc[mi][ni];
            #pragma unroll
            for (int j = 0; j < 4; ++j) {
                int mm = m0 + j;
                int b = mm >> sl, n = mm & smask;
                u16 val = f2b(v[j]);
                if (which == 0) { if (qb) qb[(((size_t)b * HH + h) * seq + n) * 64 + d] = val; }
                else if (which == 1) { if (kb) kb[(((size_t)b * HH + h) * seq + n) * 64 + d] = val; }
                else vt[(((size_t)b * HH + h) * 64 + d) * seq + n] = val;
            }
        }
    }
}

// ---------------------------------------------------------------------------
// Proj GEMM: A bf16 [M,512] @ Wt bf16 [512,512]^T + bscale*bias
// ---------------------------------------------------------------------------
template<bool OUTBF>
__global__ __launch_bounds__(256) void gemm_proj_mfma_k(
    const u16* __restrict__ A, const u16* __restrict__ Wt,
    const float* __restrict__ bias, float bscale, void* __restrict__ outp)
{
    __shared__ __align__(16) short As[128][72];
    __shared__ __align__(16) short Bs[128][72];
    const int tid = threadIdx.x;
    const int wave = tid >> 6, lane = tid & 63;
    const int lr = lane & 15, lk = (lane >> 4) * 8;
    const int rb = blockIdx.y * 128, cb = blockIdx.x * 128;
    const int wr = (wave >> 1) * 64, wc = (wave & 1) * 64;
    f32x4 acc[4][4] = {};
    const int srow = tid >> 3, skc = (tid & 7) * 8;
    for (int k0 = 0; k0 < 512; k0 += 64) {
        #pragma unroll
        for (int it = 0; it < 4; ++it) {
            int row = it * 32 + srow;
            *reinterpret_cast<bf16x8*>(&As[row][skc]) =
                *reinterpret_cast<const bf16x8*>(A + (size_t)(rb + row) * 512 + k0 + skc);
            *reinterpret_cast<bf16x8*>(&Bs[row][skc]) =
                *reinterpret_cast<const bf16x8*>(Wt + (size_t)(cb + row) * 512 + k0 + skc);
        }
        __syncthreads();
        #pragma unroll
        for (int ks = 0; ks < 2; ++ks) {
            bf16x8 af[4], bf_[4];
            #pragma unroll
            for (int mi = 0; mi < 4; ++mi)
                af[mi] = *reinterpret_cast<const bf16x8*>(&As[wr + mi * 16 + lr][ks * 32 + lk]);
            #pragma unroll
            for (int ni = 0; ni < 4; ++ni)
                bf_[ni] = *reinterpret_cast<const bf16x8*>(&Bs[wc + ni * 16 + lr][ks * 32 + lk]);
            #pragma unroll
            for (int mi = 0; mi < 4; ++mi)
                #pragma unroll
                for (int ni = 0; ni < 4; ++ni)
                    acc[mi][ni] = mfma16(af[mi], bf_[ni], acc[mi][ni]);
        }
        __syncthreads();
    }
    #pragma unroll
    for (int mi = 0; mi < 4; ++mi) {
        int m0 = rb + wr + mi * 16 + (lane >> 4) * 4;
        #pragma unroll
        for (int ni = 0; ni < 4; ++ni) {
            int c = cb + wc + ni * 16 + lr;
            float bv = bscale * bias[c];
            f32x4 v = acc[mi][ni];
            #pragma unroll
            for (int j = 0; j < 4; ++j) {
                size_t o = (size_t)(m0 + j) * 512 + c;
                if (OUTBF) reinterpret_cast<u16*>(outp)[o] = f2b(v[j] + bv);
                else       reinterpret_cast<float*>(outp)[o] = v[j] + bv;
            }
        }
    }
}

// ---------------------------------------------------------------------------
// Scores: S[bh,r,c] = SCALE * Aq[bh,r,:64] . Bk[bh,c,:64], bf16 out
// ---------------------------------------------------------------------------
__global__ __launch_bounds__(256) void scores_mfma_k(
    const u16* __restrict__ Aq, const u16* __restrict__ Bk,
    u16* __restrict__ S, int R, int C)
{
    __shared__ __align__(16) short As[128][72];
    __shared__ __align__(16) short Bs[128][72];
    const int tid = threadIdx.x;
    const int wave = tid >> 6, lane = tid & 63;
    const int lr = lane & 15, lk = (lane >> 4) * 8;
    const int bh = blockIdx.z;
    const int rb = blockIdx.y * 128, cb = blockIdx.x * 128;
    const int wr = (wave >> 1) * 64, wc = (wave & 1) * 64;
    const u16* Ap = Aq + (size_t)bh * R * 64;
    const u16* Bp = Bk + (size_t)bh * C * 64;
    const int srow = tid >> 3, skc = (tid & 7) * 8;
    #pragma unroll
    for (int it = 0; it < 4; ++it) {
        int row = it * 32 + srow;
        *reinterpret_cast<bf16x8*>(&As[row][skc]) =
            *reinterpret_cast<const bf16x8*>(Ap + (size_t)(rb + row) * 64 + skc);
        *reinterpret_cast<bf16x8*>(&Bs[row][skc]) =
            *reinterpret_cast<const bf16x8*>(Bp + (size_t)(cb + row) * 64 + skc);
    }
    __syncthreads();
    f32x4 acc[4][4] = {};
    #pragma unroll
    for (int ks = 0; ks < 2; ++ks) {
        bf16x8 af[4], bf_[4];
        #pragma unroll
        for (int mi = 0; mi < 4; ++mi)
            af[mi] = *reinterpret_cast<const bf16x8*>(&As[wr + mi * 16 + lr][ks * 32 + lk]);
        #pragma unroll
        for (int ni = 0; ni < 4; ++ni)
            bf_[ni] = *reinterpret_cast<const bf16x8*>(&Bs[wc + ni * 16 + lr][ks * 32 + lk]);
        #pragma unroll
        for (int mi = 0; mi < 4; ++mi)
            #pragma unroll
            for (int ni = 0; ni < 4; ++ni)
                acc[mi][ni] = mfma16(af[mi], bf_[ni], acc[mi][ni]);
    }
    #pragma unroll
    for (int mi = 0; mi < 4; ++mi) {
        int r0 = rb + wr + mi * 16 + (lane >> 4) * 4;
        #pragma unroll
        for (int ni = 0; ni < 4; ++ni) {
            int c = cb + wc + ni * 16 + lr;
            f32x4 v = acc[mi][ni];
            #pragma unroll
            for (int j = 0; j < 4; ++j)
                S[((size_t)bh * R + r0 + j) * C + c] = f2b(v[j] * SCALEF);
        }
    }
}

// ---------------------------------------------------------------------------
// PV: out[b, r, h*64+d] (bf16, merged) = sum_src P[bh,r,:C] @ V[bh,:C,d]
// V given transposed: Vt [bh, 64, C]
// ---------------------------------------------------------------------------
template<int NSRC>
__global__ __launch_bounds__(256) void pv_mfma_k(
    const u16* __restrict__ P1, const u16* __restrict__ V1t,
    const u16* __restrict__ P2, const u16* __restrict__ V2t,
    u16* __restrict__ out, int R, int C)
{
    __shared__ __align__(16) short As[128][72];
    __shared__ __align__(16) short Bs[64][72];
    const int tid = threadIdx.x;
    const int wave = tid >> 6, lane = tid & 63;
    const int lr = lane & 15, lk = (lane >> 4) * 8;
    const int bh = blockIdx.y, b = bh >> 3, h = bh & 7;
    const int rb = blockIdx.x * 128;
    const int wr = wave * 32;
    f32x4 acc[2][4] = {};
    const int srow = tid >> 3, skc = (tid & 7) * 8;
    #pragma unroll
    for (int src = 0; src < NSRC; ++src) {
        const u16* P = src ? P2 : P1;
        const u16* Vt = src ? V2t : V1t;
        const u16* Pb = P + (size_t)bh * R * C + (size_t)rb * C;
        const u16* Vb = Vt + (size_t)bh * 64 * C;
        for (int c0 = 0; c0 < C; c0 += 64) {
            #pragma unroll
            for (int it = 0; it < 4; ++it) {
                int row = it * 32 + srow;
                *reinterpret_cast<bf16x8*>(&As[row][skc]) =
                    *reinterpret_cast<const bf16x8*>(Pb + (size_t)row * C + c0 + skc);
            }
            #pragma unroll
            for (int it = 0; it < 2; ++it) {
                int row = it * 32 + srow;
                *reinterpret_cast<bf16x8*>(&Bs[row][skc]) =
                    *reinterpret_cast<const bf16x8*>(Vb + (size_t)row * C + c0 + skc);
            }
            __syncthreads();
            #pragma unroll
            for (int ks = 0; ks < 2; ++ks) {
                bf16x8 af[2], bf_[4];
                #pragma unroll
                for (int mi = 0; mi < 2; ++mi)
                    af[mi] = *reinterpret_cast<const bf16x8*>(&As[wr + mi * 16 + lr][ks * 32 + lk]);
                #pragma unroll
                for (int ni = 0; ni < 4; ++ni)
                    bf_[ni] = *reinterpret_cast<const bf16x8*>(&Bs[ni * 16 + lr][ks * 32 + lk]);
                #pragma unroll
                for (int mi = 0; mi < 2; ++mi)
                    #pragma unroll
                    for (int ni = 0; ni < 4; ++ni)
                        acc[mi][ni] = mfma16(af[mi], bf_[ni], acc[mi][ni]);
            }
            __syncthreads();
        }
    }
    #pragma unroll
    for (int mi = 0; mi < 2; ++mi) {
        int r0 = rb + wr + mi * 16 + (lane >> 4) * 4;
        #pragma unroll
        for (int ni = 0; ni < 4; ++ni) {
            int d = ni * 16 + lr;
            f32x4 v = acc[mi][ni];
            #pragma unroll
            for (int j = 0; j < 4; ++j)
                out[((size_t)(b * R + r0 + j)) * 512 + h * 64 + d] = f2b(v[j]);
        }
    }
}

// ---------------------------------------------------------------------------
// main orientation: per (bh,k) f32 bin-sums of |S| (bf16), argmax -> MO
// ---------------------------------------------------------------------------
__global__ __launch_bounds__(256) void main_ori_k(
    const u16* __restrict__ S, const int* __restrict__ polar,
    int* __restrict__ MO)
{
    const int blk = blockIdx.x;          // bh*KLL + k
    const int bh = blk >> 8, k = blk & 255, b = bh >> 3;
    const int tid = threadIdx.x;
    const int wave = tid >> 6, lane = tid & 63;
    const u16* row = S + (size_t)blk * XLL;
    const int* prow = polar + ((size_t)b * KLL + k) * XLL;
    int c = tid * 4;
    ushort4 sv = *reinterpret_cast<const ushort4*>(row + c);
    int4 p4 = *reinterpret_cast<const int4*>(prow + c);
    float av[4] = { fabsf(b2f(sv.x)), fabsf(b2f(sv.y)), fabsf(b2f(sv.z)), fabsf(b2f(sv.w)) };
    int pc[4] = { p4.x, p4.y, p4.z, p4.w };
    float bins[8] = {};
    #pragma unroll
    for (int j = 0; j < 4; ++j) {
        int p = pc[j]; p = p < 0 ? 0 : (p > 7 ? 7 : p);
        #pragma unroll
        for (int o = 0; o < 8; ++o) bins[o] += (p == o) ? av[j] : 0.0f;
    }
    #pragma unroll
    for (int o = 0; o < 8; ++o) bins[o] = wred_sum(bins[o]);
    __shared__ float sred[4][8];
    if (lane == 0)
        #pragma unroll
        for (int o = 0; o < 8; ++o) sred[wave][o] = bins[o];
    __syncthreads();
    if (tid == 0) {
        int best = 0; float bv = -1.0f;
        #pragma unroll
        for (int o = 0; o < 8; ++o) {
            float s = sred[0][o] + sred[1][o] + sred[2][o] + sred[3][o];
            if (s > bv) { bv = s; best = o; }
        }
        MO[blk] = best;
    }
}

// ---------------------------------------------------------------------------
// Softmax (bf16 in-place). CC=1024: 1 row/block (R=256 rows per bh).
// CC=256: 4 rows/block, wave per row (R=1024 rows per bh).
// BIASMODE: 0 none; 1 row-index is k; 2 col-index is k. MASKT: mask [bh,c,r].
// ---------------------------------------------------------------------------
template<int BIASMODE, int MASKT, int CC>
__global__ __launch_bounds__(256) void softmax_k(
    u16* __restrict__ S, const int* __restrict__ mask, float maskval,
    const int* __restrict__ rd, const int* __restrict__ polar,
    const float* __restrict__ dis, const float* __restrict__ pemb,
    const int* __restrict__ MO)
{
    const int tid = threadIdx.x;
    const int wave = tid >> 6, lane = tid & 63;
    if (CC == 1024) {
        const int row_g = blockIdx.x;                 // bh*256 + r
        const int bh = row_g >> 8, r = row_g & 255;
        const int b = bh >> 3, h = bh & 7;
        const int c = tid * 4;
        u16* rowp = S + (size_t)row_g * 1024;
        ushort4 sv = *reinterpret_cast<const ushort4*>(rowp + c);
        float s[4] = { b2f(sv.x), b2f(sv.y), b2f(sv.z), b2f(sv.w) };
        #pragma unroll
        for (int j = 0; j < 4; ++j) {
            size_t midx = MASKT ? ((size_t)bh * 1024 + c + j) * 256 + r
                                : (size_t)row_g * 1024 + c + j;
            if (mask[midx]) s[j] = maskval;
        }
        if (BIASMODE == 1) {
            size_t pbase = ((size_t)b * KLL + r) * XLL + c;
            int4 rd4 = *reinterpret_cast<const int4*>(rd + pbase);
            int4 pp4 = *reinterpret_cast<const int4*>(polar + pbase);
            int mo = MO[bh * KLL + r];
            int rr[4] = { rd4.x, rd4.y, rd4.z, rd4.w };
            int pp[4] = { pp4.x, pp4.y, pp4.z, pp4.w };
            #pragma unroll
            for (int j = 0; j < 4; ++j) {
                int p = pp[j]; p = p < 0 ? 0 : (p > 7 ? 7 : p);
                s[j] += dis[rr[j] * HH + h] + pemb[(p - mo + 8) & 7];
            }
        }
        float lmax = fmaxf(fmaxf(s[0], s[1]), fmaxf(s[2], s[3]));
        lmax = wred_max(lmax);
        __shared__ float smx[4], ssm[4];
        if (lane == 0) smx[wave] = lmax;
        __syncthreads();
        float m = fmaxf(fmaxf(smx[0], smx[1]), fmaxf(smx[2], smx[3]));
        float lsum = 0.0f;
        #pragma unroll
        for (int j = 0; j < 4; ++j) { s[j] = __expf(s[j] - m); lsum += s[j]; }
        lsum = wred_sum(lsum);
        if (lane == 0) ssm[wave] = lsum;
        __syncthreads();
        float inv = 1.0f / (ssm[0] + ssm[1] + ssm[2] + ssm[3]);
        ushort4 ov = { f2b(s[0] * inv), f2b(s[1] * inv), f2b(s[2] * inv), f2b(s[3] * inv) };
        *reinterpret_cast<ushort4*>(rowp + c) = ov;
    } else {
        const int row_g = blockIdx.x * 4 + wave;      // bh*1024 + r
        const int bh = row_g >> 10, r = row_g & 1023;
        const int b = bh >> 3, h = bh & 7;
        const int c = lane * 4;
        u16* rowp = S + (size_t)row_g * 256;
        ushort4 sv = *reinterpret_cast<const ushort4*>(rowp + c);
        float s[4] = { b2f(sv.x), b2f(sv.y), b2f(sv.z), b2f(sv.w) };
        int4 mv = *reinterpret_cast<const int4*>(mask + (size_t)row_g * 256 + c);
        int mm[4] = { mv.x, mv.y, mv.z, mv.w };
        #pragma unroll
        for (int j = 0; j < 4; ++j) if (mm[j]) s[j] = maskval;
        if (BIASMODE == 2) {
            int4 mo4 = *reinterpret_cast<const int4*>(MO + bh * KLL + c);
            int mo[4] = { mo4.x, mo4.y, mo4.z, mo4.w };
            #pragma unroll
            for (int j = 0; j < 4; ++j) {
                size_t pidx = ((size_t)b * KLL + c + j) * XLL + r;
                int rv = rd[pidx];
                int p = polar[pidx]; p = p < 0 ? 0 : (p > 7 ? 7 : p);
                s[j] += dis[rv * HH + h] + pemb[(p - mo[j] + 8) & 7];
            }
        }
        float lmax = fmaxf(fmaxf(s[0], s[1]), fmaxf(s[2], s[3]));
        float m = wred_max(lmax);
        float lsum = 0.0f;
        #pragma unroll
        for (int j = 0; j < 4; ++j) { s[j] = __expf(s[j] - m); lsum += s[j]; }
        float inv = 1.0f / wred_sum(lsum);
        ushort4 ov = { f2b(s[0] * inv), f2b(s[1] * inv), f2b(s[2] * inv), f2b(s[3] * inv) };
        *reinterpret_cast<ushort4*>(rowp + c) = ov;
    }
}

// ---------------------------------------------------------------------------
extern "C" void kernel_launch(void* const* d_in, const int* in_sizes, int n_in,
                              void* d_out, int out_size, void* d_ws, size_t ws_size,
                              hipStream_t stream)
{
    const float* x        = (const float*)d_in[0];
    const float* kernal   = (const float*)d_in[1];
    const float* i_x      = (const float*)d_in[2];
    const float* i_kernal = (const float*)d_in[3];
    const int*   rd       = (const int*)d_in[4];
    const int*   polar    = (const int*)d_in[5];
    const int*   att      = (const int*)d_in[6];
    const int*   i_att    = (const int*)d_in[7];
    const int*   cross    = (const int*)d_in[8];
    const float* Wqkv     = (const float*)d_in[9];
    const float* Wqkv_i   = (const float*)d_in[10];
    const float* Wqkv_i2  = (const float*)d_in[11];
    const float* Wproj    = (const float*)d_in[12];
    const float* bproj    = (const float*)d_in[13];
    const float* Wproj_i  = (const float*)d_in[14];
    const float* bproj_i  = (const float*)d_in[15];
    const float* Wproj_i2 = (const float*)d_in[16];
    const float* bproj_i2 = (const float*)d_in[17];
    const float* dis      = (const float*)d_in[18];
    const float* pemb     = (const float*)d_in[19];

    float* out = (float*)d_out;
    float* x_out   = out;
    float* k_out   = out + (size_t)BB * XLL * DIMM;
    float* i_x_out = k_out + (size_t)BB * KLL * DIMM;

    char* ws = (char*)d_ws;
    size_t off = 0;
    auto alloc = [&](size_t bytes) { void* p = ws + off; off += (bytes + 255) & ~(size_t)255; return p; };

    const size_t NAX = (size_t)BB * XLL * DIMM;   // 2,097,152 elems
    const size_t NAK = (size_t)BB * KLL * DIMM;   //   524,288
    const size_t NHX = (size_t)BHH * XLL * HEADD; // 2,097,152
    const size_t NHK = (size_t)BHH * KLL * HEADD; //   524,288
    const size_t NS  = (size_t)BHH * KLL * XLL;   // 8,388,608

    u16* WqkvT    = (u16*)alloc(3 * DIMM * DIMM * 3 * 2 / 3 * 1);  // 1536*512*2
    // (explicit sizes below to avoid arithmetic typos)
    off -= ((size_t)(3 * DIMM * DIMM * 3 * 2 / 3 * 1) + 255) & ~(size_t)255;
    WqkvT          = (u16*)alloc((size_t)1536 * 512 * 2);
    u16* WqkvIT    = (u16*)alloc((size_t)1536 * 512 * 2);
    u16* WqkvI2T   = (u16*)alloc((size_t)1536 * 512 * 2);
    u16* WprojT    = (u16*)alloc((size_t)512 * 512 * 2);
    u16* WprojIT   = (u16*)alloc((size_t)512 * 512 * 2);
    u16* WprojI2T  = (u16*)alloc((size_t)512 * 512 * 2);
    u16* Abf       = (u16*)alloc(NAX * 2);
    u16* Q    = (u16*)alloc(NHX * 2);
    u16* KX   = (u16*)alloc(NHX * 2);
    u16* VXt  = (u16*)alloc(NHX * 2);
    u16* KQ   = (u16*)alloc(NHK * 2);
    u16* KK   = (u16*)alloc(NHK * 2);
    u16* KVt  = (u16*)alloc(NHK * 2);
    u16* IQ   = (u16*)alloc(NHX * 2);
    u16* IK   = (u16*)alloc(NHX * 2);
    u16* IVt  = (u16*)alloc(NHX * 2);
    u16* IKQ  = (u16*)alloc(NHK * 2);
    u16* IKK  = (u16*)alloc(NHK * 2);
    u16* IKVt = (u16*)alloc(NHK * 2);
    u16* K2K  = (u16*)alloc(NHK * 2);
    u16* K2Vt = (u16*)alloc(NHK * 2);
    u16* SPa  = (u16*)alloc(NS * 2);
    u16* SPb  = (u16*)alloc(NS * 2);
    u16* KMb  = (u16*)alloc(NAK * 2);
    u16* XMb  = (u16*)alloc(NAX * 2);
    u16* IKOUTb = (u16*)alloc(NAK * 2);
    int* MO   = (int*)alloc((size_t)BHH * KLL * 4);

    dim3 blk(256);

    // weight transposes
    transpose_cast_k<<<dim3(48, 16), blk, 0, stream>>>(Wqkv,     WqkvT,   512, 1536);
    transpose_cast_k<<<dim3(48, 16), blk, 0, stream>>>(Wqkv_i,   WqkvIT,  512, 1536);
    transpose_cast_k<<<dim3(48, 16), blk, 0, stream>>>(Wqkv_i2,  WqkvI2T, 512, 1536);
    transpose_cast_k<<<dim3(16, 16), blk, 0, stream>>>(Wproj,    WprojT,  512, 512);
    transpose_cast_k<<<dim3(16, 16), blk, 0, stream>>>(Wproj_i,  WprojIT, 512, 512);
    transpose_cast_k<<<dim3(16, 16), blk, 0, stream>>>(Wproj_i2, WprojI2T,512, 512);

    // QKV projections (Abf reused; stream-ordered)
    cast_bf16_k<<<dim3(1024), blk, 0, stream>>>(x, Abf, (int)(NAX / 8));
    gemm_qkv_mfma_k<<<dim3(12, 32), blk, 0, stream>>>(Abf, WqkvT, Q, KX, VXt, 10);
    cast_bf16_k<<<dim3(256), blk, 0, stream>>>(kernal, Abf, (int)(NAK / 8));
    gemm_qkv_mfma_k<<<dim3(12, 8), blk, 0, stream>>>(Abf, WqkvT, KQ, KK, KVt, 8);
    cast_bf16_k<<<dim3(1024), blk, 0, stream>>>(i_x, Abf, (int)(NAX / 8));
    gemm_qkv_mfma_k<<<dim3(12, 32), blk, 0, stream>>>(Abf, WqkvIT, IQ, IK, IVt, 10);
    cast_bf16_k<<<dim3(256), blk, 0, stream>>>(i_kernal, Abf, (int)(NAK / 8));
    gemm_qkv_mfma_k<<<dim3(12, 8), blk, 0, stream>>>(Abf, WqkvIT, IKQ, IKK, IKVt, 8);

    // --- branch 1: k_out ---
    scores_mfma_k<<<dim3(8, 2, BHH), blk, 0, stream>>>(KQ, KX, SPa, KLL, XLL);
    main_ori_k<<<dim3(BHH * KLL), blk, 0, stream>>>(SPa, polar, MO);
    softmax_k<1, 1, 1024><<<dim3(BHH * KLL), blk, 0, stream>>>(SPa, att, -1e6f, rd, polar, dis, pemb, MO);
    pv_mfma_k<1><<<dim3(2, BHH), blk, 0, stream>>>(SPa, VXt, nullptr, nullptr, KMb, KLL, XLL);
    gemm_proj_mfma_k<false><<<dim3(4, 8), blk, 0, stream>>>(KMb, WprojT, bproj, 1.0f, k_out);

    // --- branch 2: x_out ---
    scores_mfma_k<<<dim3(2, 8, BHH), blk, 0, stream>>>(Q, KK, SPa, XLL, KLL);
    softmax_k<2, 0, 256><<<dim3(BHH * XLL / 4), blk, 0, stream>>>(SPa, att, -1e9f, rd, polar, dis, pemb, MO);
    scores_mfma_k<<<dim3(2, 8, BHH), blk, 0, stream>>>(Q, IKK, SPb, XLL, KLL);
    softmax_k<0, 0, 256><<<dim3(BHH * XLL / 4), blk, 0, stream>>>(SPb, cross, -1e9f, rd, polar, dis, pemb, MO);
    pv_mfma_k<2><<<dim3(8, BHH), blk, 0, stream>>>(SPa, KVt, SPb, IKVt, XMb, XLL, KLL);
    gemm_proj_mfma_k<false><<<dim3(4, 32), blk, 0, stream>>>(XMb, WprojT, bproj, 2.0f, x_out);

    // --- branch 3: i_x_out ---
    scores_mfma_k<<<dim3(8, 2, BHH), blk, 0, stream>>>(IKQ, IK, SPa, KLL, XLL);
    softmax_k<0, 1, 1024><<<dim3(BHH * KLL), blk, 0, stream>>>(SPa, i_att, -1e9f, rd, polar, dis, pemb, MO);
    pv_mfma_k<1><<<dim3(2, BHH), blk, 0, stream>>>(SPa, IVt, nullptr, nullptr, KMb, KLL, XLL);
    gemm_proj_mfma_k<true><<<dim3(4, 8), blk, 0, stream>>>(KMb, WprojIT, bproj_i, 1.0f, IKOUTb);
    gemm_qkv_mfma_k<<<dim3(12, 8), blk, 0, stream>>>(IKOUTb, WqkvI2T, nullptr, K2K, K2Vt, 8);
    scores_mfma_k<<<dim3(2, 8, BHH), blk, 0, stream>>>(IQ, K2K, SPa, XLL, KLL);
    softmax_k<0, 0, 256><<<dim3(BHH * XLL / 4), blk, 0, stream>>>(SPa, i_att, -1e9f, rd, polar, dis, pemb, MO);
    pv_mfma_k<1><<<dim3(8, BHH), blk, 0, stream>>>(SPa, K2Vt, nullptr, nullptr, XMb, XLL, KLL);
    gemm_proj_mfma_k<false><<<dim3(4, 32), blk, 0, stream>>>(XMb, WprojI2T, bproj_i2, 1.0f, i_x_out);

    (void)in_sizes; (void)n_in; (void)out_size; (void)ws_size;
}

// Round 3
// 436.569 us; speedup vs baseline: 2.4692x; 1.1195x over previous
//
#include <hip/hip_runtime.h>
#include <cstddef>
#include <cstdint>

#define BB 4
#define HH 8
#define HEADD 64
#define DIMM 512
#define XLL 1024
#define KLL 256
#define BHH (BB*HH)
#define SCALEF 0.125f

typedef __attribute__((ext_vector_type(8))) short bf16x8;
typedef __attribute__((ext_vector_type(8))) unsigned short u16x8;
typedef __attribute__((ext_vector_type(4))) float f32x4;
typedef unsigned short u16;

__device__ __forceinline__ u16 f2b(float f) {
    unsigned int u = __builtin_bit_cast(unsigned int, f);
    u = u + 0x7fffu + ((u >> 16) & 1u);
    return (u16)(u >> 16);
}
__device__ __forceinline__ float b2f(u16 h) {
    unsigned int u = ((unsigned int)h) << 16;
    return __builtin_bit_cast(float, u);
}
__device__ __forceinline__ f32x4 mfma16(bf16x8 a, bf16x8 b, f32x4 c) {
    return __builtin_amdgcn_mfma_f32_16x16x32_bf16(a, b, c, 0, 0, 0);
}
__device__ __forceinline__ float wred_max(float v) {
    #pragma unroll
    for (int o = 1; o < 64; o <<= 1) v = fmaxf(v, __shfl_xor(v, o, 64));
    return v;
}
__device__ __forceinline__ float wred_sum(float v) {
    #pragma unroll
    for (int o = 1; o < 64; o <<= 1) v += __shfl_xor(v, o, 64);
    return v;
}

// ---------------------------------------------------------------------------
// f32 -> bf16 cast, 8 elems/thread
// ---------------------------------------------------------------------------
__global__ __launch_bounds__(256) void cast_bf16_k(
    const float* __restrict__ in, u16* __restrict__ out, int n8)
{
    int i = blockIdx.x * 256 + threadIdx.x;
    if (i >= n8) return;
    const float4* p = reinterpret_cast<const float4*>(in) + (size_t)i * 2;
    float4 a = p[0], b = p[1];
    u16x8 o;
    o[0] = f2b(a.x); o[1] = f2b(a.y); o[2] = f2b(a.z); o[3] = f2b(a.w);
    o[4] = f2b(b.x); o[5] = f2b(b.y); o[6] = f2b(b.z); o[7] = f2b(b.w);
    *reinterpret_cast<u16x8*>(out + (size_t)i * 8) = o;
}

// ---------------------------------------------------------------------------
// W [K][N] f32  ->  Wt [N][K] bf16
// ---------------------------------------------------------------------------
__global__ __launch_bounds__(256) void transpose_cast_k(
    const float* __restrict__ W, u16* __restrict__ Wt, int K, int N)
{
    __shared__ float t[32][33];
    int bx = blockIdx.x, by = blockIdx.y;
    int tx = threadIdx.x & 31, ty = threadIdx.x >> 5;
    #pragma unroll
    for (int r = ty; r < 32; r += 8)
        t[r][tx] = W[(size_t)(by * 32 + r) * N + bx * 32 + tx];
    __syncthreads();
    #pragma unroll
    for (int r = ty; r < 32; r += 8)
        Wt[(size_t)(bx * 32 + r) * K + by * 32 + tx] = f2b(t[tx][r]);
}

// ---------------------------------------------------------------------------
// mask int32 [bh, 1024(x), 256(k)] -> uint8 [bh, 256(k), 1024(x)]
// ---------------------------------------------------------------------------
__global__ __launch_bounds__(256) void mask_t8_k(
    const int* __restrict__ m, unsigned char* __restrict__ mt)
{
    __shared__ unsigned char t[32][33];
    const int bh = blockIdx.z, xt = blockIdx.x, kt = blockIdx.y;
    const int tx = threadIdx.x & 31, ty = threadIdx.x >> 5;
    #pragma unroll
    for (int r = ty; r < 32; r += 8)
        t[r][tx] = (unsigned char)(m[((size_t)bh * 1024 + xt * 32 + r) * 256 + kt * 32 + tx] != 0);
    __syncthreads();
    #pragma unroll
    for (int r = ty; r < 32; r += 8)
        mt[((size_t)bh * 256 + kt * 32 + r) * 1024 + xt * 32 + tx] = t[tx][r];
}

// ---------------------------------------------------------------------------
// QKV GEMM: A bf16 [M,512] @ Wt bf16 [1536,512]^T, epilogue split per head.
// q,k -> [b,h,n,64] bf16; v -> [b,h,64,n] bf16 (transposed for PV B-operand)
// ---------------------------------------------------------------------------
__global__ __launch_bounds__(256) void gemm_qkv_mfma_k(
    const u16* __restrict__ A, const u16* __restrict__ Wt,
    u16* __restrict__ qb, u16* __restrict__ kb, u16* __restrict__ vt,
    int sl)
{
    __shared__ __align__(16) short As[128][72];
    __shared__ __align__(16) short Bs[128][72];
    const int tid = threadIdx.x;
    const int wave = tid >> 6, lane = tid & 63;
    const int lr = lane & 15, lk = (lane >> 4) * 8;
    const int rb = blockIdx.y * 128, cb = blockIdx.x * 128;
    const int wr = (wave >> 1) * 64, wc = (wave & 1) * 64;
    const int seq = 1 << sl, smask = seq - 1;
    f32x4 acc[4][4] = {};
    const int srow = tid >> 3, skc = (tid & 7) * 8;
    for (int k0 = 0; k0 < 512; k0 += 64) {
        #pragma unroll
        for (int it = 0; it < 4; ++it) {
            int row = it * 32 + srow;
            *reinterpret_cast<bf16x8*>(&As[row][skc]) =
                *reinterpret_cast<const bf16x8*>(A + (size_t)(rb + row) * 512 + k0 + skc);
            *reinterpret_cast<bf16x8*>(&Bs[row][skc]) =
                *reinterpret_cast<const bf16x8*>(Wt + (size_t)(cb + row) * 512 + k0 + skc);
        }
        __syncthreads();
        #pragma unroll
        for (int ks = 0; ks < 2; ++ks) {
            bf16x8 af[4], bf_[4];
            #pragma unroll
            for (int mi = 0; mi < 4; ++mi)
                af[mi] = *reinterpret_cast<const bf16x8*>(&As[wr + mi * 16 + lr][ks * 32 + lk]);
            #pragma unroll
            for (int ni = 0; ni < 4; ++ni)
                bf_[ni] = *reinterpret_cast<const bf16x8*>(&Bs[wc + ni * 16 + lr][ks * 32 + lk]);
            #pragma unroll
            for (int mi = 0; mi < 4; ++mi)
                #pragma unroll
                for (int ni = 0; ni < 4; ++ni)
                    acc[mi][ni] = mfma16(af[mi], bf_[ni], acc[mi][ni]);
        }
        __syncthreads();
    }
    #pragma unroll
    for (int mi = 0; mi < 4; ++mi) {
        int m0 = rb + wr + mi * 16 + (lane >> 4) * 4;
        #pragma unroll
        for (int ni = 0; ni < 4; ++ni) {
            int c = cb + wc + ni * 16 + lr;
            int which = c >> 9, h = (c >> 6) & 7, d = c & 63;
            f32x4 v = acc[mi][ni];
            #pragma unroll
            for (int j = 0; j < 4; ++j) {
                int mm = m0 + j;
                int b = mm >> sl, n = mm & smask;
                u16 val = f2b(v[j]);
                if (which == 0) { if (qb) qb[(((size_t)b * HH + h) * seq + n) * 64 + d] = val; }
                else if (which == 1) { if (kb) kb[(((size_t)b * HH + h) * seq + n) * 64 + d] = val; }
                else vt[(((size_t)b * HH + h) * 64 + d) * seq + n] = val;
            }
        }
    }
}

// ---------------------------------------------------------------------------
// Proj GEMM: A bf16 [M,512] @ Wt bf16 [512,512]^T + bscale*bias
// ---------------------------------------------------------------------------
template<bool OUTBF>
__global__ __launch_bounds__(256) void gemm_proj_mfma_k(
    const u16* __restrict__ A, const u16* __restrict__ Wt,
    const float* __restrict__ bias, float bscale, void* __restrict__ outp)
{
    __shared__ __align__(16) short As[128][72];
    __shared__ __align__(16) short Bs[128][72];
    const int tid = threadIdx.x;
    const int wave = tid >> 6, lane = tid & 63;
    const int lr = lane & 15, lk = (lane >> 4) * 8;
    const int rb = blockIdx.y * 128, cb = blockIdx.x * 128;
    const int wr = (wave >> 1) * 64, wc = (wave & 1) * 64;
    f32x4 acc[4][4] = {};
    const int srow = tid >> 3, skc = (tid & 7) * 8;
    for (int k0 = 0; k0 < 512; k0 += 64) {
        #pragma unroll
        for (int it = 0; it < 4; ++it) {
            int row = it * 32 + srow;
            *reinterpret_cast<bf16x8*>(&As[row][skc]) =
                *reinterpret_cast<const bf16x8*>(A + (size_t)(rb + row) * 512 + k0 + skc);
            *reinterpret_cast<bf16x8*>(&Bs[row][skc]) =
                *reinterpret_cast<const bf16x8*>(Wt + (size_t)(cb + row) * 512 + k0 + skc);
        }
        __syncthreads();
        #pragma unroll
        for (int ks = 0; ks < 2; ++ks) {
            bf16x8 af[4], bf_[4];
            #pragma unroll
            for (int mi = 0; mi < 4; ++mi)
                af[mi] = *reinterpret_cast<const bf16x8*>(&As[wr + mi * 16 + lr][ks * 32 + lk]);
            #pragma unroll
            for (int ni = 0; ni < 4; ++ni)
                bf_[ni] = *reinterpret_cast<const bf16x8*>(&Bs[wc + ni * 16 + lr][ks * 32 + lk]);
            #pragma unroll
            for (int mi = 0; mi < 4; ++mi)
                #pragma unroll
                for (int ni = 0; ni < 4; ++ni)
                    acc[mi][ni] = mfma16(af[mi], bf_[ni], acc[mi][ni]);
        }
        __syncthreads();
    }
    #pragma unroll
    for (int mi = 0; mi < 4; ++mi) {
        int m0 = rb + wr + mi * 16 + (lane >> 4) * 4;
        #pragma unroll
        for (int ni = 0; ni < 4; ++ni) {
            int c = cb + wc + ni * 16 + lr;
            float bv = bscale * bias[c];
            f32x4 v = acc[mi][ni];
            #pragma unroll
            for (int j = 0; j < 4; ++j) {
                size_t o = (size_t)(m0 + j) * 512 + c;
                if (OUTBF) reinterpret_cast<u16*>(outp)[o] = f2b(v[j] + bv);
                else       reinterpret_cast<float*>(outp)[o] = v[j] + bv;
            }
        }
    }
}

// ---------------------------------------------------------------------------
// Scores: S[bh,r,c] = SCALE * Aq[bh,r,:64] . Bk[bh,c,:64], bf16 out
// ---------------------------------------------------------------------------
__global__ __launch_bounds__(256) void scores_mfma_k(
    const u16* __restrict__ Aq, const u16* __restrict__ Bk,
    u16* __restrict__ S, int R, int C)
{
    __shared__ __align__(16) short As[128][72];
    __shared__ __align__(16) short Bs[128][72];
    const int tid = threadIdx.x;
    const int wave = tid >> 6, lane = tid & 63;
    const int lr = lane & 15, lk = (lane >> 4) * 8;
    const int bh = blockIdx.z;
    const int rb = blockIdx.y * 128, cb = blockIdx.x * 128;
    const int wr = (wave >> 1) * 64, wc = (wave & 1) * 64;
    const u16* Ap = Aq + (size_t)bh * R * 64;
    const u16* Bp = Bk + (size_t)bh * C * 64;
    const int srow = tid >> 3, skc = (tid & 7) * 8;
    #pragma unroll
    for (int it = 0; it < 4; ++it) {
        int row = it * 32 + srow;
        *reinterpret_cast<bf16x8*>(&As[row][skc]) =
            *reinterpret_cast<const bf16x8*>(Ap + (size_t)(rb + row) * 64 + skc);
        *reinterpret_cast<bf16x8*>(&Bs[row][skc]) =
            *reinterpret_cast<const bf16x8*>(Bp + (size_t)(cb + row) * 64 + skc);
    }
    __syncthreads();
    f32x4 acc[4][4] = {};
    #pragma unroll
    for (int ks = 0; ks < 2; ++ks) {
        bf16x8 af[4], bf_[4];
        #pragma unroll
        for (int mi = 0; mi < 4; ++mi)
            af[mi] = *reinterpret_cast<const bf16x8*>(&As[wr + mi * 16 + lr][ks * 32 + lk]);
        #pragma unroll
        for (int ni = 0; ni < 4; ++ni)
            bf_[ni] = *reinterpret_cast<const bf16x8*>(&Bs[wc + ni * 16 + lr][ks * 32 + lk]);
        #pragma unroll
        for (int mi = 0; mi < 4; ++mi)
            #pragma unroll
            for (int ni = 0; ni < 4; ++ni)
                acc[mi][ni] = mfma16(af[mi], bf_[ni], acc[mi][ni]);
    }
    #pragma unroll
    for (int mi = 0; mi < 4; ++mi) {
        int r0 = rb + wr + mi * 16 + (lane >> 4) * 4;
        #pragma unroll
        for (int ni = 0; ni < 4; ++ni) {
            int c = cb + wc + ni * 16 + lr;
            f32x4 v = acc[mi][ni];
            #pragma unroll
            for (int j = 0; j < 4; ++j)
                S[((size_t)bh * R + r0 + j) * C + c] = f2b(v[j] * SCALEF);
        }
    }
}

// ---------------------------------------------------------------------------
// PV: out[b, r, h*64+d] (bf16, merged) = P[bh,r,:C] @ V[bh,:C,d]; Vt [bh,64,C]
// ---------------------------------------------------------------------------
template<int NSRC>
__global__ __launch_bounds__(256) void pv_mfma_k(
    const u16* __restrict__ P1, const u16* __restrict__ V1t,
    const u16* __restrict__ P2, const u16* __restrict__ V2t,
    u16* __restrict__ out, int R, int C)
{
    __shared__ __align__(16) short As[128][72];
    __shared__ __align__(16) short Bs[64][72];
    const int tid = threadIdx.x;
    const int wave = tid >> 6, lane = tid & 63;
    const int lr = lane & 15, lk = (lane >> 4) * 8;
    const int bh = blockIdx.y, b = bh >> 3, h = bh & 7;
    const int rb = blockIdx.x * 128;
    const int wr = wave * 32;
    f32x4 acc[2][4] = {};
    const int srow = tid >> 3, skc = (tid & 7) * 8;
    #pragma unroll
    for (int src = 0; src < NSRC; ++src) {
        const u16* P = src ? P2 : P1;
        const u16* Vt = src ? V2t : V1t;
        const u16* Pb = P + (size_t)bh * R * C + (size_t)rb * C;
        const u16* Vb = Vt + (size_t)bh * 64 * C;
        for (int c0 = 0; c0 < C; c0 += 64) {
            #pragma unroll
            for (int it = 0; it < 4; ++it) {
                int row = it * 32 + srow;
                *reinterpret_cast<bf16x8*>(&As[row][skc]) =
                    *reinterpret_cast<const bf16x8*>(Pb + (size_t)row * C + c0 + skc);
            }
            #pragma unroll
            for (int it = 0; it < 2; ++it) {
                int row = it * 32 + srow;
                *reinterpret_cast<bf16x8*>(&Bs[row][skc]) =
                    *reinterpret_cast<const bf16x8*>(Vb + (size_t)row * C + c0 + skc);
            }
            __syncthreads();
            #pragma unroll
            for (int ks = 0; ks < 2; ++ks) {
                bf16x8 af[2], bf_[4];
                #pragma unroll
                for (int mi = 0; mi < 2; ++mi)
                    af[mi] = *reinterpret_cast<const bf16x8*>(&As[wr + mi * 16 + lr][ks * 32 + lk]);
                #pragma unroll
                for (int ni = 0; ni < 4; ++ni)
                    bf_[ni] = *reinterpret_cast<const bf16x8*>(&Bs[ni * 16 + lr][ks * 32 + lk]);
                #pragma unroll
                for (int mi = 0; mi < 2; ++mi)
                    #pragma unroll
                    for (int ni = 0; ni < 4; ++ni)
                        acc[mi][ni] = mfma16(af[mi], bf_[ni], acc[mi][ni]);
            }
            __syncthreads();
        }
    }
    #pragma unroll
    for (int mi = 0; mi < 2; ++mi) {
        int r0 = rb + wr + mi * 16 + (lane >> 4) * 4;
        #pragma unroll
        for (int ni = 0; ni < 4; ++ni) {
            int d = ni * 16 + lr;
            f32x4 v = acc[mi][ni];
            #pragma unroll
            for (int j = 0; j < 4; ++j)
                out[((size_t)(b * R + r0 + j)) * 512 + h * 64 + d] = f2b(v[j]);
        }
    }
}

// ---------------------------------------------------------------------------
// Wide softmax (C=1024 rows of S), fused main_ori (BIAS=1). maskT uint8 [bh,k,x].
// ---------------------------------------------------------------------------
template<int BIAS>
__global__ __launch_bounds__(256) void softmax_wide_k(
    u16* __restrict__ S, const unsigned char* __restrict__ maskT, float maskval,
    const int* __restrict__ rd, const int* __restrict__ polar,
    const float* __restrict__ dis, const float* __restrict__ pemb,
    int* __restrict__ MO)
{
    const int row_g = blockIdx.x;                 // bh*256 + k
    const int bh = row_g >> 8, k = row_g & 255;
    const int b = bh >> 3, h = bh & 7;
    const int tid = threadIdx.x;
    const int wave = tid >> 6, lane = tid & 63;
    const int c = tid * 4;
    u16* rowp = S + (size_t)row_g * 1024;
    ushort4 sv = *reinterpret_cast<const ushort4*>(rowp + c);
    float s[4] = { b2f(sv.x), b2f(sv.y), b2f(sv.z), b2f(sv.w) };
    uchar4 mk = *reinterpret_cast<const uchar4*>(maskT + (size_t)row_g * 1024 + c);
    unsigned char mka[4] = { mk.x, mk.y, mk.z, mk.w };

    __shared__ float sred[4][8];
    __shared__ int smo;
    __shared__ float swv[4];

    int mo = 0;
    int rr[4] = {}, pp[4] = {};
    if (BIAS) {
        size_t pbase = ((size_t)b * 256 + k) * 1024 + c;
        int4 r4 = *reinterpret_cast<const int4*>(rd + pbase);
        int4 p4 = *reinterpret_cast<const int4*>(polar + pbase);
        rr[0] = r4.x; rr[1] = r4.y; rr[2] = r4.z; rr[3] = r4.w;
        int pt[4] = { p4.x, p4.y, p4.z, p4.w };
        #pragma unroll
        for (int j = 0; j < 4; ++j) { int p = pt[j]; pp[j] = p < 0 ? 0 : (p > 7 ? 7 : p); }
        float bins[8] = {};
        #pragma unroll
        for (int j = 0; j < 4; ++j) {
            float av = fabsf(s[j]);
            #pragma unroll
            for (int o = 0; o < 8; ++o) bins[o] += (pp[j] == o) ? av : 0.0f;
        }
        #pragma unroll
        for (int o = 0; o < 8; ++o) bins[o] = wred_sum(bins[o]);
        if (lane == 0) {
            #pragma unroll
            for (int o = 0; o < 8; ++o) sred[wave][o] = bins[o];
        }
        __syncthreads();
        if (tid == 0) {
            int best = 0; float bv = -1.0f;
            #pragma unroll
            for (int o = 0; o < 8; ++o) {
                float t = sred[0][o] + sred[1][o] + sred[2][o] + sred[3][o];
                if (t > bv) { bv = t; best = o; }
            }
            smo = best;
            MO[row_g] = best;
        }
        __syncthreads();
        mo = smo;
    }
    #pragma unroll
    for (int j = 0; j < 4; ++j) if (mka[j]) s[j] = maskval;
    if (BIAS) {
        #pragma unroll
        for (int j = 0; j < 4; ++j)
            s[j] += dis[rr[j] * HH + h] + pemb[(pp[j] - mo + 8) & 7];
    }
    float lm = fmaxf(fmaxf(s[0], s[1]), fmaxf(s[2], s[3]));
    lm = wred_max(lm);
    if (lane == 0) swv[wave] = lm;
    __syncthreads();
    float m = fmaxf(fmaxf(swv[0], swv[1]), fmaxf(swv[2], swv[3]));
    __syncthreads();
    float ls = 0.0f;
    #pragma unroll
    for (int j = 0; j < 4; ++j) { s[j] = __expf(s[j] - m); ls += s[j]; }
    ls = wred_sum(ls);
    if (lane == 0) swv[wave] = ls;
    __syncthreads();
    float inv = 1.0f / (swv[0] + swv[1] + swv[2] + swv[3]);
    ushort4 ov = { f2b(s[0] * inv), f2b(s[1] * inv), f2b(s[2] * inv), f2b(s[3] * inv) };
    *reinterpret_cast<ushort4*>(rowp + c) = ov;
}

// ---------------------------------------------------------------------------
// Fused attention for R=1024 (x rows), C=256 (k cols):
// scores (Q@K^T*SCALE) -> mask (-1e9 direct [bh,x,k]) -> optional rd/polar bias
// -> softmax -> PV -> merged bf16 out.  NSRC=2 accumulates two (K,V,mask) sets.
// 512 threads (8 waves), 128-row tile, LDS: Q | union(K,P) | V | red.
// ---------------------------------------------------------------------------
template<int NSRC, bool BIAS0>
__global__ __launch_bounds__(512) void attn_xk_fused_k(
    const u16* __restrict__ Qp,
    const u16* __restrict__ K1, const u16* __restrict__ V1t, const int* __restrict__ M1,
    const u16* __restrict__ K2, const u16* __restrict__ V2t, const int* __restrict__ M2,
    const int* __restrict__ rd, const int* __restrict__ polar,
    const float* __restrict__ dis, const float* __restrict__ pemb,
    const int* __restrict__ MO,
    u16* __restrict__ outm)
{
    const int tid = threadIdx.x;
    const int w = tid >> 6, lane = tid & 63;
    const int lr = lane & 15, lg = lane >> 4;
    const int lk = lg * 8;
    const int bh = blockIdx.y, b = bh >> 3, h = bh & 7;
    const int rb = blockIdx.x * 128;
    const int wrow = (w >> 2) * 64, wcol = (w & 3) * 64;   // scores tiling
    const int wrow2 = w * 16;                               // pv tiling
    const int wcg = w & 3;

    __shared__ __align__(16) char lds[18432 + 67584 + 33792 + 2048];
    short* Qs = (short*)lds;                       // [128][72]
    short* KP = (short*)(lds + 18432);             // Ks [256][72] | Ps [128][264]
    short* Vsl = (short*)(lds + 18432 + 67584);    // [64][264]
    float* red = (float*)(lds + 18432 + 67584 + 33792); // [128][4]

    // stage Q tile [128][64]
    {
        const u16* Qb = Qp + ((size_t)bh * 1024 + rb) * 64;
        #pragma unroll
        for (int it = 0; it < 2; ++it) {
            int chunk = tid + it * 512;
            int r_ = chunk >> 3, c8 = (chunk & 7) * 8;
            *reinterpret_cast<bf16x8*>(&Qs[r_ * 72 + c8]) =
                *reinterpret_cast<const bf16x8*>(Qb + (size_t)r_ * 64 + c8);
        }
    }

    f32x4 acc2[4] = {};   // PV accumulator over d (4 ni fragments)

    #pragma unroll
    for (int s = 0; s < NSRC; ++s) {
        const u16* Kp = (s == 0) ? K1 : K2;
        const u16* Vp = (s == 0) ? V1t : V2t;
        const int* Mp = (s == 0) ? M1 : M2;
        __syncthreads();   // prior PV done (and Q staged on iter 0)
        // stage K [256][64] and V [64][256]
        #pragma unroll
        for (int it = 0; it < 4; ++it) {
            int chunk = tid + it * 512;
            int r_ = chunk >> 3, c8 = (chunk & 7) * 8;
            *reinterpret_cast<bf16x8*>(&KP[r_ * 72 + c8]) =
                *reinterpret_cast<const bf16x8*>(Kp + ((size_t)bh * 256 + r_) * 64 + c8);
            int vd = chunk >> 5, vc8 = (chunk & 31) * 8;
            *reinterpret_cast<bf16x8*>(&Vsl[vd * 264 + vc8]) =
                *reinterpret_cast<const bf16x8*>(Vp + ((size_t)bh * 64 + vd) * 256 + vc8);
        }
        __syncthreads();
        // scores: 64x64 per wave, K=64
        f32x4 acc[4][4] = {};
        #pragma unroll
        for (int ks = 0; ks < 2; ++ks) {
            bf16x8 af[4], bfv[4];
            #pragma unroll
            for (int mi = 0; mi < 4; ++mi)
                af[mi] = *reinterpret_cast<const bf16x8*>(&Qs[(wrow + mi * 16 + lr) * 72 + ks * 32 + lk]);
            #pragma unroll
            for (int ni = 0; ni < 4; ++ni)
                bfv[ni] = *reinterpret_cast<const bf16x8*>(&KP[(wcol + ni * 16 + lr) * 72 + ks * 32 + lk]);
            #pragma unroll
            for (int mi = 0; mi < 4; ++mi)
                #pragma unroll
                for (int ni = 0; ni < 4; ++ni)
                    acc[mi][ni] = mfma16(af[mi], bfv[ni], acc[mi][ni]);
        }
        // scale + mask + optional bias
        #pragma unroll
        for (int ni = 0; ni < 4; ++ni) {
            const int cK = wcol + ni * 16 + lr;
            int mo_ = 0;
            if (BIAS0 && s == 0) mo_ = MO[bh * 256 + cK];
            #pragma unroll
            for (int mi = 0; mi < 4; ++mi) {
                #pragma unroll
                for (int j = 0; j < 4; ++j) {
                    const int rXj = rb + wrow + mi * 16 + lg * 4 + j;
                    float sv_ = acc[mi][ni][j] * SCALEF;
                    if (Mp[((size_t)bh * 1024 + rXj) * 256 + cK]) sv_ = -1e9f;
                    if (BIAS0 && s == 0) {
                        size_t pidx = ((size_t)b * 256 + cK) * 1024 + rXj;
                        int rv = rd[pidx];
                        int p = polar[pidx]; p = p < 0 ? 0 : (p > 7 ? 7 : p);
                        sv_ += dis[rv * HH + h] + pemb[(p - mo_ + 8) & 7];
                    }
                    acc[mi][ni][j] = sv_;
                }
            }
        }
        // row max (cross 16 lanes, then cross 4 col-waves via LDS)
        float rmax[4][4];
        #pragma unroll
        for (int mi = 0; mi < 4; ++mi)
            #pragma unroll
            for (int j = 0; j < 4; ++j) {
                float v = fmaxf(fmaxf(acc[mi][0][j], acc[mi][1][j]),
                                fmaxf(acc[mi][2][j], acc[mi][3][j]));
                #pragma unroll
                for (int o = 1; o < 16; o <<= 1) v = fmaxf(v, __shfl_xor(v, o, 64));
                rmax[mi][j] = v;
            }
        if (lr == 0) {
            #pragma unroll
            for (int mi = 0; mi < 4; ++mi)
                #pragma unroll
                for (int j = 0; j < 4; ++j)
                    red[(wrow + mi * 16 + lg * 4 + j) * 4 + wcg] = rmax[mi][j];
        }
        __syncthreads();
        float rowm[4][4];
        #pragma unroll
        for (int mi = 0; mi < 4; ++mi)
            #pragma unroll
            for (int j = 0; j < 4; ++j) {
                f32x4 r4 = *reinterpret_cast<f32x4*>(&red[(wrow + mi * 16 + lg * 4 + j) * 4]);
                rowm[mi][j] = fmaxf(fmaxf(r4[0], r4[1]), fmaxf(r4[2], r4[3]));
            }
        __syncthreads();   // all max reads done before sum writes
        // exp + row sum
        float rsum[4][4];
        #pragma unroll
        for (int mi = 0; mi < 4; ++mi)
            #pragma unroll
            for (int j = 0; j < 4; ++j) {
                float m_ = rowm[mi][j];
                float e0 = __expf(acc[mi][0][j] - m_);
                float e1 = __expf(acc[mi][1][j] - m_);
                float e2 = __expf(acc[mi][2][j] - m_);
                float e3 = __expf(acc[mi][3][j] - m_);
                acc[mi][0][j] = e0; acc[mi][1][j] = e1;
                acc[mi][2][j] = e2; acc[mi][3][j] = e3;
                float v = (e0 + e1) + (e2 + e3);
                #pragma unroll
                for (int o = 1; o < 16; o <<= 1) v += __shfl_xor(v, o, 64);
                rsum[mi][j] = v;
            }
        if (lr == 0) {
            #pragma unroll
            for (int mi = 0; mi < 4; ++mi)
                #pragma unroll
                for (int j = 0; j < 4; ++j)
                    red[(wrow + mi * 16 + lg * 4 + j) * 4 + wcg] = rsum[mi][j];
        }
        __syncthreads();
        // normalize + write P (aliases K region; all K reads finished above)
        #pragma unroll
        for (int mi = 0; mi < 4; ++mi)
            #pragma unroll
            for (int j = 0; j < 4; ++j) {
                f32x4 r4 = *reinterpret_cast<f32x4*>(&red[(wrow + mi * 16 + lg * 4 + j) * 4]);
                float inv = 1.0f / (((r4[0] + r4[1]) + (r4[2] + r4[3])));
                int rloc = wrow + mi * 16 + lg * 4 + j;
                #pragma unroll
                for (int ni = 0; ni < 4; ++ni)
                    KP[rloc * 264 + wcol + ni * 16 + lr] = (short)f2b(acc[mi][ni][j] * inv);
            }
        __syncthreads();
        // PV: 16 rows per wave, N=64, K=256
        #pragma unroll
        for (int kc = 0; kc < 8; ++kc) {
            bf16x8 ap = *reinterpret_cast<const bf16x8*>(&KP[(wrow2 + lr) * 264 + kc * 32 + lk]);
            #pragma unroll
            for (int ni = 0; ni < 4; ++ni) {
                bf16x8 vv = *reinterpret_cast<const bf16x8*>(&Vsl[(ni * 16 + lr) * 264 + kc * 32 + lk]);
                acc2[ni] = mfma16(ap, vv, acc2[ni]);
            }
        }
    }
    // epilogue: merged bf16 out [b, x, 512]
    #pragma unroll
    for (int ni = 0; ni < 4; ++ni) {
        int d = ni * 16 + lr;
        f32x4 v = acc2[ni];
        #pragma unroll
        for (int j = 0; j < 4; ++j) {
            int row = rb + wrow2 + lg * 4 + j;
            outm[((size_t)(b * 1024 + row)) * 512 + h * 64 + d] = f2b(v[j]);
        }
    }
}

// ---------------------------------------------------------------------------
extern "C" void kernel_launch(void* const* d_in, const int* in_sizes, int n_in,
                              void* d_out, int out_size, void* d_ws, size_t ws_size,
                              hipStream_t stream)
{
    const float* x        = (const float*)d_in[0];
    const float* kernal   = (const float*)d_in[1];
    const float* i_x      = (const float*)d_in[2];
    const float* i_kernal = (const float*)d_in[3];
    const int*   rd       = (const int*)d_in[4];
    const int*   polar    = (const int*)d_in[5];
    const int*   att      = (const int*)d_in[6];
    const int*   i_att    = (const int*)d_in[7];
    const int*   cross    = (const int*)d_in[8];
    const float* Wqkv     = (const float*)d_in[9];
    const float* Wqkv_i   = (const float*)d_in[10];
    const float* Wqkv_i2  = (const float*)d_in[11];
    const float* Wproj    = (const float*)d_in[12];
    const float* bproj    = (const float*)d_in[13];
    const float* Wproj_i  = (const float*)d_in[14];
    const float* bproj_i  = (const float*)d_in[15];
    const float* Wproj_i2 = (const float*)d_in[16];
    const float* bproj_i2 = (const float*)d_in[17];
    const float* dis      = (const float*)d_in[18];
    const float* pemb     = (const float*)d_in[19];

    float* out = (float*)d_out;
    float* x_out   = out;
    float* k_out   = out + (size_t)BB * XLL * DIMM;
    float* i_x_out = k_out + (size_t)BB * KLL * DIMM;

    char* ws = (char*)d_ws;
    size_t off = 0;
    auto alloc = [&](size_t bytes) { void* p = ws + off; off += (bytes + 255) & ~(size_t)255; return p; };

    const size_t NAX = (size_t)BB * XLL * DIMM;
    const size_t NAK = (size_t)BB * KLL * DIMM;
    const size_t NHX = (size_t)BHH * XLL * HEADD;
    const size_t NHK = (size_t)BHH * KLL * HEADD;
    const size_t NS  = (size_t)BHH * KLL * XLL;

    u16* WqkvT     = (u16*)alloc((size_t)1536 * 512 * 2);
    u16* WqkvIT    = (u16*)alloc((size_t)1536 * 512 * 2);
    u16* WqkvI2T   = (u16*)alloc((size_t)1536 * 512 * 2);
    u16* WprojT    = (u16*)alloc((size_t)512 * 512 * 2);
    u16* WprojIT   = (u16*)alloc((size_t)512 * 512 * 2);
    u16* WprojI2T  = (u16*)alloc((size_t)512 * 512 * 2);
    u16* Abf       = (u16*)alloc(NAX * 2);
    u16* Q    = (u16*)alloc(NHX * 2);
    u16* KX   = (u16*)alloc(NHX * 2);
    u16* VXt  = (u16*)alloc(NHX * 2);
    u16* KQ   = (u16*)alloc(NHK * 2);
    u16* KK   = (u16*)alloc(NHK * 2);
    u16* KVt  = (u16*)alloc(NHK * 2);
    u16* IQ   = (u16*)alloc(NHX * 2);
    u16* IK   = (u16*)alloc(NHX * 2);
    u16* IVt  = (u16*)alloc(NHX * 2);
    u16* IKQ  = (u16*)alloc(NHK * 2);
    u16* IKK  = (u16*)alloc(NHK * 2);
    u16* IKVt = (u16*)alloc(NHK * 2);
    u16* K2K  = (u16*)alloc(NHK * 2);
    u16* K2Vt = (u16*)alloc(NHK * 2);
    u16* SPa  = (u16*)alloc(NS * 2);
    u16* KMb  = (u16*)alloc(NAK * 2);
    u16* XMb  = (u16*)alloc(NAX * 2);
    u16* IKOUTb = (u16*)alloc(NAK * 2);
    unsigned char* attT8  = (unsigned char*)alloc(NS);
    unsigned char* iattT8 = (unsigned char*)alloc(NS);
    int* MO   = (int*)alloc((size_t)BHH * KLL * 4);

    dim3 blk(256);

    // weight transposes
    transpose_cast_k<<<dim3(48, 16), blk, 0, stream>>>(Wqkv,     WqkvT,   512, 1536);
    transpose_cast_k<<<dim3(48, 16), blk, 0, stream>>>(Wqkv_i,   WqkvIT,  512, 1536);
    transpose_cast_k<<<dim3(48, 16), blk, 0, stream>>>(Wqkv_i2,  WqkvI2T, 512, 1536);
    transpose_cast_k<<<dim3(16, 16), blk, 0, stream>>>(Wproj,    WprojT,  512, 512);
    transpose_cast_k<<<dim3(16, 16), blk, 0, stream>>>(Wproj_i,  WprojIT, 512, 512);
    transpose_cast_k<<<dim3(16, 16), blk, 0, stream>>>(Wproj_i2, WprojI2T,512, 512);

    // mask transposes to uint8 [bh,k,x]
    mask_t8_k<<<dim3(32, 8, 32), blk, 0, stream>>>(att,   attT8);
    mask_t8_k<<<dim3(32, 8, 32), blk, 0, stream>>>(i_att, iattT8);

    // QKV projections
    cast_bf16_k<<<dim3(1024), blk, 0, stream>>>(x, Abf, (int)(NAX / 8));
    gemm_qkv_mfma_k<<<dim3(12, 32), blk, 0, stream>>>(Abf, WqkvT, Q, KX, VXt, 10);
    cast_bf16_k<<<dim3(256), blk, 0, stream>>>(kernal, Abf, (int)(NAK / 8));
    gemm_qkv_mfma_k<<<dim3(12, 8), blk, 0, stream>>>(Abf, WqkvT, KQ, KK, KVt, 8);
    cast_bf16_k<<<dim3(1024), blk, 0, stream>>>(i_x, Abf, (int)(NAX / 8));
    gemm_qkv_mfma_k<<<dim3(12, 32), blk, 0, stream>>>(Abf, WqkvIT, IQ, IK, IVt, 10);
    cast_bf16_k<<<dim3(256), blk, 0, stream>>>(i_kernal, Abf, (int)(NAK / 8));
    gemm_qkv_mfma_k<<<dim3(12, 8), blk, 0, stream>>>(Abf, WqkvIT, IKQ, IKK, IKVt, 8);

    // --- branch 1: k_out ---
    scores_mfma_k<<<dim3(8, 2, BHH), blk, 0, stream>>>(KQ, KX, SPa, KLL, XLL);
    softmax_wide_k<1><<<dim3(BHH * KLL), blk, 0, stream>>>(SPa, attT8, -1e6f, rd, polar, dis, pemb, MO);
    pv_mfma_k<1><<<dim3(2, BHH), blk, 0, stream>>>(SPa, VXt, nullptr, nullptr, KMb, KLL, XLL);
    gemm_proj_mfma_k<false><<<dim3(4, 8), blk, 0, stream>>>(KMb, WprojT, bproj, 1.0f, k_out);

    // --- branch 2: x_out (fused dual attention) ---
    attn_xk_fused_k<2, true><<<dim3(8, BHH), dim3(512), 0, stream>>>(
        Q, KK, KVt, att, IKK, IKVt, cross, rd, polar, dis, pemb, MO, XMb);
    gemm_proj_mfma_k<false><<<dim3(4, 32), blk, 0, stream>>>(XMb, WprojT, bproj, 2.0f, x_out);

    // --- branch 3: i_x_out ---
    scores_mfma_k<<<dim3(8, 2, BHH), blk, 0, stream>>>(IKQ, IK, SPa, KLL, XLL);
    softmax_wide_k<0><<<dim3(BHH * KLL), blk, 0, stream>>>(SPa, iattT8, -1e9f, rd, polar, dis, pemb, MO);
    pv_mfma_k<1><<<dim3(2, BHH), blk, 0, stream>>>(SPa, IVt, nullptr, nullptr, KMb, KLL, XLL);
    gemm_proj_mfma_k<true><<<dim3(4, 8), blk, 0, stream>>>(KMb, WprojIT, bproj_i, 1.0f, IKOUTb);
    gemm_qkv_mfma_k<<<dim3(12, 8), blk, 0, stream>>>(IKOUTb, WqkvI2T, nullptr, K2K, K2Vt, 8);
    attn_xk_fused_k<1, false><<<dim3(8, BHH), dim3(512), 0, stream>>>(
        IQ, K2K, K2Vt, i_att, nullptr, nullptr, nullptr, rd, polar, dis, pemb, MO, XMb);
    gemm_proj_mfma_k<false><<<dim3(4, 32), blk, 0, stream>>>(XMb, WprojI2T, bproj_i2, 1.0f, i_x_out);

    (void)in_sizes; (void)n_in; (void)out_size; (void)ws_size;
}